// Round 12
// baseline (330.299 us; speedup 1.0000x reference)
//
#include <hip/hip_runtime.h>
#include <hip/hip_fp16.h>

#define B 64
#define N 4096
#define M 128

constexpr int T   = 1024;   // 16 waves/CU, 1 block/CU (128 KiB LDS)
constexpr int CPB = 16;     // channels per job -> 8 packed complex planes
constexpr int NWG = 256;    // one block per CU; each block runs 2 jobs pipelined

// LDS slot for plane f (0..7), index p (0..4095): 5-bit XOR fold spreads all
// stage strides (<=2-way, free); per-plane rotation f<<2 makes the 4 planes
// touched by one load/unpack instruction land on distinct banks.
__device__ __forceinline__ int slot(int f, int p) {
    return (f << 12) + (p & ~31) + ((p ^ (p >> 5) ^ (p >> 9) ^ (f << 2)) & 31);
}
// octal-digit reverse of 12-bit index (DIF output slot of frequency k)
__device__ __forceinline__ int rev12(int k) {
    return ((k & 7) << 9) | (((k >> 3) & 7) << 6) | (((k >> 6) & 7) << 3) | ((k >> 9) & 7);
}

__device__ __forceinline__ float2 cadd(float2 a, float2 b){ return make_float2(a.x+b.x, a.y+b.y); }
__device__ __forceinline__ float2 csub(float2 a, float2 b){ return make_float2(a.x-b.x, a.y-b.y); }
__device__ __forceinline__ float2 cmul(float2 a, float2 b){ return make_float2(a.x*b.x - a.y*b.y, a.x*b.y + a.y*b.x); }
__device__ __forceinline__ float2 mulnegi(float2 a){ return make_float2(a.y, -a.x); }
__device__ __forceinline__ float2 muli(float2 a)  { return make_float2(-a.y, a.x); }
__device__ __forceinline__ float2 cis(float ang){ float s, c; __sincosf(ang, &s, &c); return make_float2(c, s); }
__device__ __forceinline__ float2 h2f(__half2 h){ return __half22float2(h); }
__device__ __forceinline__ __half2 f2h(float2 v){ return __floats2half2_rn(v.x, v.y); }

// forward DFT8 in place (W8 = e^{-i pi/4})
__device__ __forceinline__ void dft8(float2 t[8]) {
    float2 e0=cadd(t[0],t[4]), e1=csub(t[0],t[4]);
    float2 e2=cadd(t[2],t[6]), e3=csub(t[2],t[6]);
    float2 E0=cadd(e0,e2), E2=csub(e0,e2);
    float2 E1=cadd(e1,mulnegi(e3)), E3=cadd(e1,muli(e3));
    float2 o0=cadd(t[1],t[5]), o1=csub(t[1],t[5]);
    float2 o2=cadd(t[3],t[7]), o3=csub(t[3],t[7]);
    float2 O0=cadd(o0,o2), O2=csub(o0,o2);
    float2 O1=cadd(o1,mulnegi(o3)), O3=cadd(o1,muli(o3));
    const float C = 0.70710678118654752f;
    float2 w1O1 = make_float2(C*(O1.x+O1.y), C*(O1.y-O1.x));
    float2 w2O2 = mulnegi(O2);
    float2 w3O3 = make_float2(C*(O3.y-O3.x), -C*(O3.x+O3.y));
    t[0]=cadd(E0,O0);   t[4]=csub(E0,O0);
    t[1]=cadd(E1,w1O1); t[5]=csub(E1,w1O1);
    t[2]=cadd(E2,w2O2); t[6]=csub(E2,w2O2);
    t[3]=cadd(E3,w3O3); t[7]=csub(E3,w3O3);
}

// One radix-8 DIF stage, span S. In-place on identical slots per task ->
// barriers only between stages. Each wave touches a single plane.
template<int S>
__device__ __forceinline__ void stage(__half2* z, int tid) {
    #pragma unroll
    for (int it = 0; it < 4; ++it) {
        const int qv = tid + (it << 10);   // 0..4095
        const int f  = qv >> 9;            // plane 0..7 (constant per wave)
        const int qq = qv & 511;
        int G, j;
        if      (S == 512) { G = 0;               j = qq;      }
        else if (S == 64)  { G = (qq >> 6) << 9;  j = qq & 63; }
        else if (S == 8)   { G = (qq >> 3) << 6;  j = qq & 7;  }
        else               { G = qq << 3;         j = 0;       }
        const int nbase = G + j;
        int idx[8];
        #pragma unroll
        for (int c = 0; c < 8; ++c) idx[c] = slot(f, nbase + c * S);
        float2 r[8];
        #pragma unroll
        for (int c = 0; c < 8; ++c) r[c] = h2f(z[idx[c]]);
        dft8(r);
        if (S > 1) {
            float2 w1 = cis(-6.2831853071795864f * (float)j / (float)(8 * S));
            float2 w = w1;
            #pragma unroll
            for (int k = 1; k < 8; ++k) { r[k] = cmul(r[k], w); w = cmul(w, w1); }
        }
        #pragma unroll
        for (int c = 0; c < 8; ++c) z[idx[c]] = f2h(r[c]);
    }
}

__device__ __forceinline__ void run_stages(__half2* z, int tid) {
    stage<512>(z, tid); __syncthreads();
    stage<64 >(z, tid); __syncthreads();
    stage<8  >(z, tid); __syncthreads();
    stage<1  >(z, tid); __syncthreads();
}

// Hermitian unpack (freq k lives at slot rev12(k)) + full-64B-segment stores
__device__ __forceinline__ void unpack_store(const __half2* z, int tid,
                                             float* outRe, float* outIm,
                                             size_t rbase) {
    #pragma unroll
    for (int it = 0; it < 16; ++it) {
        int u = tid + (it << 10);
        int k = u >> 2, c = u & 3;
        int kk = (N - k) & (N - 1);
        int rk = rev12(k), rm = rev12(kk);
        float2 Zk0 = h2f(z[slot(2*c,   rk)]);
        float2 Zm0 = h2f(z[slot(2*c,   rm)]);
        float2 Zk1 = h2f(z[slot(2*c+1, rk)]);
        float2 Zm1 = h2f(z[slot(2*c+1, rm)]);
        float4 re, im;
        re.x = 0.5f * (Zk0.x + Zm0.x); im.x = 0.5f * (Zk0.y - Zm0.y);
        re.y = 0.5f * (Zk0.y + Zm0.y); im.y = 0.5f * (Zm0.x - Zk0.x);
        re.z = 0.5f * (Zk1.x + Zm1.x); im.z = 0.5f * (Zk1.y - Zm1.y);
        re.w = 0.5f * (Zk1.y + Zm1.y); im.w = 0.5f * (Zm1.x - Zk1.x);
        *(float4*)(outRe + rbase + (size_t)k * M + (c << 2)) = re;
        *(float4*)(outIm + rbase + (size_t)k * M + (c << 2)) = im;
    }
}

__global__ __launch_bounds__(T, 4)
void fft_one(const float* __restrict__ x, float* __restrict__ out) {
    extern __shared__ __half2 z[];   // 8 planes x 4096, 128 KiB

    // 256 blocks = 64 batches x 4 block-pairs; bid%8 = b&7 -> batch co-XCD
    const int bid = blockIdx.x;
    const int b   = ((bid >> 5) << 3) | (bid & 7);
    const int qb  = (bid >> 3) & 3;
    const int tid = threadIdx.x;

    const int m0_0 = qb * CPB;          // job 0: channel groups 0..3
    const int m0_1 = (qb + 4) * CPB;    // job 1: channel groups 4..7
    const float* xb0 = x + (size_t)b * N * M + m0_0;
    const float* xb1 = x + (size_t)b * N * M + m0_1;
    float* outRe = out;
    float* outIm = out + (size_t)B * N * M;

    // ---- job0 load -> LDS (full 64B row segments) ----
    #pragma unroll
    for (int it = 0; it < 16; ++it) {
        int i = tid + (it << 10);
        int n = i >> 2, c = i & 3;
        float4 v = *(const float4*)(xb0 + (size_t)n * M + (c << 2));
        z[slot(2*c,   n)] = f2h(make_float2(v.x, v.y));
        z[slot(2*c+1, n)] = f2h(make_float2(v.z, v.w));
    }
    // ---- prefetch job1 -> 64 held VGPRs; streams under job0 compute ----
    float4 pf[16];
    #pragma unroll
    for (int it = 0; it < 16; ++it) {
        int i = tid + (it << 10);
        int n = i >> 2, c = i & 3;
        pf[it] = *(const float4*)(xb1 + (size_t)n * M + (c << 2));
    }
    __syncthreads();

    run_stages(z, tid);
    unpack_store(z, tid, outRe, outIm, (size_t)b * N * M + m0_0);
    __syncthreads();   // all unpack LDS reads done before overwrite

    // ---- job1 LDS fill from prefetched regs; stores of job0 drain async ----
    #pragma unroll
    for (int it = 0; it < 16; ++it) {
        int i = tid + (it << 10);
        int n = i >> 2, c = i & 3;
        float4 v = pf[it];
        z[slot(2*c,   n)] = f2h(make_float2(v.x, v.y));
        z[slot(2*c+1, n)] = f2h(make_float2(v.z, v.w));
    }
    __syncthreads();

    run_stages(z, tid);
    unpack_store(z, tid, outRe, outIm, (size_t)b * N * M + m0_1);
}

extern "C" void kernel_launch(void* const* d_in, const int* in_sizes, int n_in,
                              void* d_out, int out_size, void* d_ws, size_t ws_size,
                              hipStream_t stream) {
    const float* x = (const float*)d_in[0];
    float* out = (float*)d_out;
    const int lds_bytes = 8 * N * (int)sizeof(__half2);   // 131072
    hipFuncSetAttribute((const void*)fft_one,
                        hipFuncAttributeMaxDynamicSharedMemorySize, lds_bytes);
    fft_one<<<NWG, T, lds_bytes, stream>>>(x, out);
}

// Round 14
// 189.167 us; speedup vs baseline: 1.7461x; 1.7461x over previous
//
#include <hip/hip_runtime.h>
#include <hip/hip_fp16.h>

#define B 64
#define N 4096
#define M 128

constexpr int T   = 512;    // 8 waves; __launch_bounds__(T,2) -> 256 VGPR budget
constexpr int NWG = 512;    // 64 batches x 8 channel-groups (16 ch each)

__device__ __forceinline__ float2 cadd(float2 a, float2 b){ return make_float2(a.x+b.x, a.y+b.y); }
__device__ __forceinline__ float2 csub(float2 a, float2 b){ return make_float2(a.x-b.x, a.y-b.y); }
__device__ __forceinline__ float2 cmul(float2 a, float2 b){ return make_float2(a.x*b.x - a.y*b.y, a.x*b.y + a.y*b.x); }
__device__ __forceinline__ float2 mulnegi(float2 a){ return make_float2(a.y, -a.x); }
__device__ __forceinline__ float2 muli(float2 a)  { return make_float2(-a.y, a.x); }
__device__ __forceinline__ float2 cis(float ang){ float s, c; __sincosf(ang, &s, &c); return make_float2(c, s); }
__device__ __forceinline__ float2 h2f(__half2 h){ return __half22float2(h); }
__device__ __forceinline__ __half2 f2h(float2 v){ return __floats2half2_rn(v.x, v.y); }

// forward DFT8 in place (W8 = e^{-i pi/4}): t_out[k] = sum_c t_in[c] W8^{ck}
__device__ __forceinline__ void dft8(float2 t[8]) {
    float2 e0=cadd(t[0],t[4]), e1=csub(t[0],t[4]);
    float2 e2=cadd(t[2],t[6]), e3=csub(t[2],t[6]);
    float2 E0=cadd(e0,e2), E2=csub(e0,e2);
    float2 E1=cadd(e1,mulnegi(e3)), E3=cadd(e1,muli(e3));
    float2 o0=cadd(t[1],t[5]), o1=csub(t[1],t[5]);
    float2 o2=cadd(t[3],t[7]), o3=csub(t[3],t[7]);
    float2 O0=cadd(o0,o2), O2=csub(o0,o2);
    float2 O1=cadd(o1,mulnegi(o3)), O3=cadd(o1,muli(o3));
    const float C = 0.70710678118654752f;
    float2 w1O1 = make_float2(C*(O1.x+O1.y), C*(O1.y-O1.x));
    float2 w2O2 = mulnegi(O2);
    float2 w3O3 = make_float2(C*(O3.y-O3.x), -C*(O3.x+O3.y));
    t[0]=cadd(E0,O0);   t[4]=csub(E0,O0);
    t[1]=cadd(E1,w1O1); t[5]=csub(E1,w1O1);
    t[2]=cadd(E2,w2O2); t[6]=csub(E2,w2O2);
    t[3]=cadd(E3,w3O3); t[7]=csub(E3,w3O3);
}

// 64-point complex FFT, fully register-resident, natural-order in/out.
// X[8c+d] = DFT8_b( W64^{bd} * DFT8_a( x[8a+b] )[d] )[c]
__device__ __forceinline__ void fft64(float2 z[64]) {
    float2 y[64];
    #pragma unroll
    for (int bb = 0; bb < 8; ++bb) {
        float2 t[8];
        #pragma unroll
        for (int a = 0; a < 8; ++a) t[a] = z[8*a+bb];
        dft8(t);
        #pragma unroll
        for (int d = 0; d < 8; ++d) y[8*bb+d] = t[d];
    }
    #pragma unroll
    for (int d = 0; d < 8; ++d) {
        float2 t[8];
        #pragma unroll
        for (int bb = 0; bb < 8; ++bb) t[bb] = y[8*bb+d];
        if (d > 0) {
            float2 w1 = cis(-6.2831853071795864f * (float)d / 64.0f);
            float2 w = w1;
            #pragma unroll
            for (int bb = 1; bb < 8; ++bb) { t[bb] = cmul(t[bb], w); w = cmul(w, w1); }
        }
        dft8(t);
        #pragma unroll
        for (int c = 0; c < 8; ++c) z[8*c+d] = t[c];
    }
}

// LDS half2 slot for (k1, n2, mc): XOR swizzle n2^(k1&7) => every phase <=2-way
__device__ __forceinline__ int lslot(int k1, int n2, int mc) {
    return (k1 << 9) | ((n2 ^ (k1 & 7)) << 3) | mc;
}

__global__ __launch_bounds__(T, 2)
void fft_one(const float* __restrict__ x, float* __restrict__ out) {
    extern __shared__ __half2 lz[];   // [k1][n2sw][mc] = 64*64*8 half2 = 128 KiB

    // bid%8 = b&7 -> all 8 channel-groups of a batch on one XCD (L2 line merge)
    const int bid = blockIdx.x;
    const int b   = ((bid >> 6) << 3) | (bid & 7);
    const int mcg = (bid >> 3) & 7;
    const int tid = threadIdx.x;
    const int mc  = tid & 7;        // packed channel pair within group
    const int rp  = tid >> 3;       // phase A: n2 ; phase B: k1 ; unpack: r

    const float* xb = x + (size_t)b * N * M + mcg * 16 + mc * 2;

    // ---- phase A: load column (n2=rp), FFT64 over n1 in registers ----
    float2 z[64];
    #pragma unroll
    for (int n1 = 0; n1 < 64; ++n1)
        z[n1] = *(const float2*)(xb + (size_t)(64 * n1 + rp) * M);
    fft64(z);                         // z[k1]

    // global twiddle: z[k1] *= W4096^{n2*k1}  (anchors + powers, short chains)
    {
        float2 ws = cis(-6.2831853071795864f * (float)rp / 4096.0f);
        float2 pw[8];
        pw[0] = make_float2(1.f, 0.f);
        #pragma unroll
        for (int d = 1; d < 8; ++d) pw[d] = cmul(pw[d-1], ws);
        float2 w8 = cmul(pw[7], ws);  // ws^8
        float2 ac = make_float2(1.f, 0.f);
        #pragma unroll
        for (int c = 0; c < 8; ++c) {
            #pragma unroll
            for (int d = 0; d < 8; ++d)
                z[8*c+d] = cmul(z[8*c+d], cmul(ac, pw[d]));
            ac = cmul(ac, w8);
        }
    }

    // transpose out: write my column into every k1-slice
    #pragma unroll
    for (int k1 = 0; k1 < 64; ++k1)
        lz[lslot(k1, rp, mc)] = f2h(z[k1]);
    __syncthreads();

    // ---- phase B: own slice k1=rp; FFT64 over n2; write Z back (self-owned) ----
    #pragma unroll
    for (int n2 = 0; n2 < 64; ++n2)
        z[n2] = h2f(lz[lslot(rp, n2, mc)]);
    fft64(z);                         // z[k2]
    #pragma unroll
    for (int k2 = 0; k2 < 64; ++k2)
        lz[lslot(rp, k2, mc)] = f2h(z[k2]);
    __syncthreads();

    // ---- Hermitian unpack + coalesced stores (rows k = 64j + r) ----
    float* outRe = out + (size_t)b * N * M + mcg * 16 + mc * 2;
    float* outIm = outRe + (size_t)B * N * M;
    const int r = rp;
    #pragma unroll 4
    for (int j = 0; j < 64; ++j) {
        int k   = (j << 6) | r;
        int kk  = (N - k) & (N - 1);
        int k1p = kk & 63, k2p = kk >> 6;
        float2 Zk = h2f(lz[lslot(r,   j,   mc)]);
        float2 Zm = h2f(lz[lslot(k1p, k2p, mc)]);
        float2 re = make_float2(0.5f * (Zk.x + Zm.x), 0.5f * (Zk.y + Zm.y));
        float2 im = make_float2(0.5f * (Zk.y - Zm.y), 0.5f * (Zm.x - Zk.x));
        *(float2*)(outRe + (size_t)k * M) = re;
        *(float2*)(outIm + (size_t)k * M) = im;
    }
}

extern "C" void kernel_launch(void* const* d_in, const int* in_sizes, int n_in,
                              void* d_out, int out_size, void* d_ws, size_t ws_size,
                              hipStream_t stream) {
    const float* x = (const float*)d_in[0];
    float* out = (float*)d_out;
    const int lds_bytes = 64 * 64 * 8 * (int)sizeof(__half2);   // 131072
    hipFuncSetAttribute((const void*)fft_one,
                        hipFuncAttributeMaxDynamicSharedMemorySize, lds_bytes);
    fft_one<<<NWG, T, lds_bytes, stream>>>(x, out);
}

// Round 17
// 122.241 us; speedup vs baseline: 2.7020x; 1.5475x over previous
//
#include <hip/hip_runtime.h>
#include <hip/hip_fp16.h>

#define B 64
#define N 4096
#define M 128

constexpr int T   = 512;    // 8 waves
constexpr int NWG = 512;    // 64 batches x 8 channel-groups (16 ch each)

__device__ __forceinline__ float2 cadd(float2 a, float2 b){ return make_float2(a.x+b.x, a.y+b.y); }
__device__ __forceinline__ float2 csub(float2 a, float2 b){ return make_float2(a.x-b.x, a.y-b.y); }
__device__ __forceinline__ float2 cmul(float2 a, float2 b){ return make_float2(a.x*b.x - a.y*b.y, a.x*b.y + a.y*b.x); }
__device__ __forceinline__ float2 mulnegi(float2 a){ return make_float2(a.y, -a.x); }
__device__ __forceinline__ float2 muli(float2 a)  { return make_float2(-a.y, a.x); }
__device__ __forceinline__ float2 cis(float ang){ float s, c; __sincosf(ang, &s, &c); return make_float2(c, s); }
__device__ __forceinline__ float2 h2f(__half2 h){ return __half22float2(h); }
__device__ __forceinline__ __half2 f2h(float2 v){ return __floats2half2_rn(v.x, v.y); }

// W64^d = cis(-2*pi*d/64), d = 0..7  (literal table, no runtime sincos)
__device__ __constant__ const float W64R[8] = {
    1.0f, 0.995184726672197f, 0.980785280403230f, 0.956940335732209f,
    0.923879532511287f, 0.881921264348355f, 0.831469612302545f, 0.773010453362737f };
__device__ __constant__ const float W64I[8] = {
    0.0f, -0.098017140329561f, -0.195090322016128f, -0.290284677254462f,
    -0.382683432365090f, -0.471396736825998f, -0.555570233019602f, -0.634393284163645f };

// forward DFT8 in place (W8 = e^{-i pi/4}): t_out[k] = sum_c t_in[c] W8^{ck}
__device__ __forceinline__ void dft8(float2 t[8]) {
    float2 e0=cadd(t[0],t[4]), e1=csub(t[0],t[4]);
    float2 e2=cadd(t[2],t[6]), e3=csub(t[2],t[6]);
    float2 E0=cadd(e0,e2), E2=csub(e0,e2);
    float2 E1=cadd(e1,mulnegi(e3)), E3=cadd(e1,muli(e3));
    float2 o0=cadd(t[1],t[5]), o1=csub(t[1],t[5]);
    float2 o2=cadd(t[3],t[7]), o3=csub(t[3],t[7]);
    float2 O0=cadd(o0,o2), O2=csub(o0,o2);
    float2 O1=cadd(o1,mulnegi(o3)), O3=cadd(o1,muli(o3));
    const float C = 0.70710678118654752f;
    float2 w1O1 = make_float2(C*(O1.x+O1.y), C*(O1.y-O1.x));
    float2 w2O2 = mulnegi(O2);
    float2 w3O3 = make_float2(C*(O3.y-O3.x), -C*(O3.x+O3.y));
    t[0]=cadd(E0,O0);   t[4]=csub(E0,O0);
    t[1]=cadd(E1,w1O1); t[5]=csub(E1,w1O1);
    t[2]=cadd(E2,w2O2); t[6]=csub(E2,w2O2);
    t[3]=cadd(E3,w3O3); t[7]=csub(E3,w3O3);
}

// LDS half2 slot for (k1, n2, mc): XOR swizzle n2^(k1&7) => every phase <=2-way
__device__ __forceinline__ int lslot(int k1, int n2, int mc) {
    return (k1 << 9) | ((n2 ^ (k1 & 7)) << 3) | mc;
}

__global__ __launch_bounds__(T, 2)
void fft_one(const float* __restrict__ x, float* __restrict__ out) {
    extern __shared__ __half2 lz[];   // [k1][n2sw][mc] = 64*64*8 half2 = 128 KiB

    // bid%8 = b&7 -> all 8 channel-groups of a batch on one XCD (L2 line merge)
    const int bid = blockIdx.x;
    const int b   = ((bid >> 6) << 3) | (bid & 7);
    const int mcg = (bid >> 3) & 7;
    const int tid = threadIdx.x;
    const int mc  = tid & 7;        // packed channel pair within group
    const int rp  = tid >> 3;       // phase A: n2 ; phase B: k1 ; unpack: r

    const float* xb = x + (size_t)b * N * M + mcg * 16 + mc * 2;

    __half2 pk[8][8];   // fp16-packed pass-1 intermediates (64 VGPRs, static idx)

    // ======== phase A: FFT64 over n1 of column n2=rp ========
    // pass 1: per column bb, load 8 rows, DFT8, pack. U_bb[d] = pk[bb][d]
    #pragma unroll
    for (int bb = 0; bb < 8; ++bb) {
        float2 t[8];
        #pragma unroll
        for (int a = 0; a < 8; ++a)
            t[a] = *(const float2*)(xb + (size_t)(64*(8*a+bb) + rp) * M);
        dft8(t);
        #pragma unroll
        for (int d = 0; d < 8; ++d) pk[bb][d] = f2h(t[d]);
    }
    // pass 2: X[8c+d] = DFT8_bb( W64^{bb*d} * U_bb[d] )[c], then global twiddle
    // W4096^{rp*(8c+d)} = (W4096^{8rp})^c * (W4096^{rp})^d, then LDS write.
    {
        const float2 ws = cis(-6.2831853071795864f * (float)rp / 4096.0f); // W4096^rp
        const float2 w8 = cis(-6.2831853071795864f * (float)rp / 512.0f);  // W4096^(8rp)
        float2 pd = make_float2(1.f, 0.f);
        #pragma unroll
        for (int d = 0; d < 8; ++d) {
            const float2 wd = make_float2(W64R[d], W64I[d]);
            float2 t[8];
            t[0] = h2f(pk[0][d]);
            float2 w = wd;
            #pragma unroll
            for (int bb = 1; bb < 8; ++bb) {
                t[bb] = cmul(h2f(pk[bb][d]), w);
                w = cmul(w, wd);
            }
            dft8(t);
            float2 ac = pd;
            #pragma unroll
            for (int c = 0; c < 8; ++c) {
                lz[lslot(8*c+d, rp, mc)] = f2h(cmul(t[c], ac));
                ac = cmul(ac, w8);
            }
            pd = cmul(pd, ws);
        }
    }
    __syncthreads();

    // ======== phase B: FFT64 over n2 of own slice k1=rp ========
    #pragma unroll
    for (int bb = 0; bb < 8; ++bb) {
        float2 t[8];
        #pragma unroll
        for (int a = 0; a < 8; ++a)
            t[a] = h2f(lz[lslot(rp, 8*a+bb, mc)]);
        dft8(t);
        #pragma unroll
        for (int d = 0; d < 8; ++d) pk[bb][d] = f2h(t[d]);
    }
    #pragma unroll
    for (int d = 0; d < 8; ++d) {
        const float2 wd = make_float2(W64R[d], W64I[d]);
        float2 t[8];
        t[0] = h2f(pk[0][d]);
        float2 w = wd;
        #pragma unroll
        for (int bb = 1; bb < 8; ++bb) {
            t[bb] = cmul(h2f(pk[bb][d]), w);
            w = cmul(w, wd);
        }
        dft8(t);
        #pragma unroll
        for (int c = 0; c < 8; ++c)
            lz[lslot(rp, 8*c+d, mc)] = f2h(t[c]);   // Z[k2=8c+d], self-owned slice
    }
    __syncthreads();

    // ======== Hermitian unpack + coalesced stores (rows k = 64j + r) ========
    float* outRe = out + (size_t)b * N * M + mcg * 16 + mc * 2;
    float* outIm = outRe + (size_t)B * N * M;
    const int r = rp;
    #pragma unroll 4
    for (int j = 0; j < 64; ++j) {
        int k   = (j << 6) | r;
        int kk  = (N - k) & (N - 1);
        int k1p = kk & 63, k2p = kk >> 6;
        float2 Zk = h2f(lz[lslot(r,   j,   mc)]);
        float2 Zm = h2f(lz[lslot(k1p, k2p, mc)]);
        float2 re = make_float2(0.5f * (Zk.x + Zm.x), 0.5f * (Zk.y + Zm.y));
        float2 im = make_float2(0.5f * (Zk.y - Zm.y), 0.5f * (Zm.x - Zk.x));
        *(float2*)(outRe + (size_t)k * M) = re;
        *(float2*)(outIm + (size_t)k * M) = im;
    }
}

extern "C" void kernel_launch(void* const* d_in, const int* in_sizes, int n_in,
                              void* d_out, int out_size, void* d_ws, size_t ws_size,
                              hipStream_t stream) {
    const float* x = (const float*)d_in[0];
    float* out = (float*)d_out;
    const int lds_bytes = 64 * 64 * 8 * (int)sizeof(__half2);   // 131072
    hipFuncSetAttribute((const void*)fft_one,
                        hipFuncAttributeMaxDynamicSharedMemorySize, lds_bytes);
    fft_one<<<NWG, T, lds_bytes, stream>>>(x, out);
}